// Round 13
// baseline (159.191 us; speedup 1.0000x reference)
//
#include <hip/hip_runtime.h>

// Problem constants
constexpr int B_ = 32, C_ = 64, H_ = 64, W_ = 64, K_ = 1024;
constexpr int NTOT = B_ * C_ * H_ * W_;          // 8388608 elements of input1/quantized
constexpr int NSP  = B_ * H_ * W_;               // 131072 spatial positions
// d_out float offsets: [0]=loss, [1..32]=input2_KL, [33..33+NTOT)=quantized(BCHW),
// [OFF_ENC .. OFF_ENC+NSP*K)=encodings
constexpr int OFF_Q   = 33;
constexpr int OFF_ENC = OFF_Q + NTOT;            // 8388641 (byte 33554564 == 4 mod 64)
constexpr long long ENC_ELEMS = (long long)NSP * K_;   // 134217728 (2^27)
// Zeroed interior: elements [ENC_HEAD, ENC_ELEMS-1) rel. to OFF_ENC; the 15 head
// elements (row 0 cols 0..14) and the last element are patched in vq_fin.
constexpr int ENC_HEAD = 15;
constexpr int ENC_NQ   = (int)((ENC_ELEMS - ENC_HEAD - 1) / 4);  // 33554428 quads
constexpr int NBLK = 2048;
constexpr int QPB  = 16384;                      // quads per block = 256 KB chunk
constexpr int LAST_NQ = ENC_NQ - (NBLK - 1) * QPB;               // 16380

typedef float v4f __attribute__((ext_vector_type(4)));

// Mega-kernel, 2048 blocks. Per block:
//  P1: zero its 256 KB chunk with a fully-unrolled constant-register store loop
//      (rocclr fillBufferAligned shape: data regs never change -> no WAR
//      waitcnts -> stores pipeline at full rate; loop amortizes launch cost).
//  P2: vmcnt(0) + barrier, then scatter the ones whose address lies in THIS
//      block's zeroed span (cross-wave ordering safe after the fence).
//  P3: quantized + loss for its own 64 rows (x_tilde words already L1-warm).
__global__ __launch_bounds__(256) void vq_mega(const float* __restrict__ input1,
                                               const int*   __restrict__ x_tilde,
                                               const float* __restrict__ weight,
                                               float* __restrict__ out,  // d_out base
                                               float* __restrict__ ws) { // d_ws partials
    const int eb  = blockIdx.x;
    const int tid = threadIdx.x;

    // ---- P1: constant zero fill, 4 KB per block-iteration, 64 iterations ----
    float* p = out + OFF_ENC + ENC_HEAD + eb * 65536 + (tid << 2);
    const v4f z = {0.f, 0.f, 0.f, 0.f};
    if (eb != NBLK - 1) {
        #pragma unroll
        for (int i = 0; i < 64; ++i)
            *reinterpret_cast<v4f*>(p + i * 1024) = z;
    } else {
        #pragma unroll
        for (int i = 0; i < 64; ++i)
            if (i * 256 + tid < LAST_NQ)
                *reinterpret_cast<v4f*>(p + i * 1024) = z;
    }
    // Drain this wave's stores to L2 (point of coherence) so the cross-thread
    // scatter below is ordered after the zeros.
    asm volatile("s_waitcnt vmcnt(0)" ::: "memory");
    __syncthreads();

    // ---- P2: scatter ones owned by this block's span ----
    if (tid < 64) {
        const int r = (eb << 6) + tid;
        const int t = x_tilde[r];
        // (tid==0 && t<15): lies before this span; covered by block eb-1's tail
        // check (eb>0) or by vq_fin's head patch (eb==0).
        if (tid > 0 || t >= ENC_HEAD)
            out[OFF_ENC + (r << 10) + t] = 1.0f;
    } else if (tid == 64) {
        const int r2 = (eb + 1) << 6;
        if (r2 < NSP) {
            const int t2 = x_tilde[r2];
            if (t2 < ENC_HEAD)                 // falls in this block's tail cols
                out[OFF_ENC + (r2 << 10) + t2] = 1.0f;
        }
    }

    // ---- P3: quantized + loss (transposed gather, 4-way channel split) ----
    const int n   = (eb << 6) + (tid & 63);          // [0, NSP)
    const int cq  = tid >> 6;                        // 0..3 -> channels 16cq..16cq+15
    const int b   = n >> 12;                         // H*W = 4096
    const int hw  = n & 4095;
    const int t   = x_tilde[n];
    const float* __restrict__ wrow = weight + (t << 6) + (cq << 4);
    const float* __restrict__ xin  = input1 + (b << 18) + (cq << 16) + hw;
    float* __restrict__ qout = out + OFF_Q + (b << 18) + (cq << 16) + hw;

    const float4 w0 = *reinterpret_cast<const float4*>(wrow);
    const float4 w1 = *reinterpret_cast<const float4*>(wrow + 4);
    const float4 w2 = *reinterpret_cast<const float4*>(wrow + 8);
    const float4 w3 = *reinterpret_cast<const float4*>(wrow + 12);
    const float wv[16] = {w0.x, w0.y, w0.z, w0.w, w1.x, w1.y, w1.z, w1.w,
                          w2.x, w2.y, w2.z, w2.w, w3.x, w3.y, w3.z, w3.w};
    float local = 0.f;
    #pragma unroll
    for (int j = 0; j < 16; ++j) {
        const float x = xin[j << 12];
        const float d = wv[j] - x;
        qout[j << 12] = x + d;       // straight-through: x + (q - x)
        local += d * d;
    }

    // wave64 reduce + one plain store per block (overwrites; no zeroing needed)
    for (int o = 32; o > 0; o >>= 1) local += __shfl_down(local, o);
    __shared__ float sm[4];
    const int lane = tid & 63, wid = tid >> 6;
    if (lane == 0) sm[wid] = local;
    __syncthreads();
    if (tid == 0) {
        ws[eb] = sm[0] + sm[1] + sm[2] + sm[3];
    }
}

// Finalize: reduce the 2048 partial sums -> loss, input2_KL passthrough, and
// the 16 edge elements the zero loop skipped.
__global__ __launch_bounds__(256) void vq_fin(const int* __restrict__ x_tilde,
                                              const float* __restrict__ ws,
                                              const float* __restrict__ kl,
                                              float* __restrict__ out) {
    const int tid = threadIdx.x;
    float local = 0.f;
    #pragma unroll
    for (int k = 0; k < 8; ++k) local += ws[tid + (k << 8)];
    for (int o = 32; o > 0; o >>= 1) local += __shfl_down(local, o);
    __shared__ float sm[4];
    if ((tid & 63) == 0) sm[tid >> 6] = local;
    __syncthreads();
    if (tid == 0) out[0] = 1.25f * (sm[0] + sm[1] + sm[2] + sm[3]) / (float)NTOT;
    if (tid >= 64 && tid < 96) out[1 + tid - 64] = kl[tid - 64];
    if (tid == 96) {
        const int t0 = x_tilde[0];
        #pragma unroll
        for (int j = 0; j < ENC_HEAD; ++j)
            out[OFF_ENC + j] = (t0 == j) ? 1.f : 0.f;      // row 0, cols 0..14
        const int tl = x_tilde[NSP - 1];
        out[OFF_ENC + (int)ENC_ELEMS - 1] = (tl == 1023) ? 1.f : 0.f;
    }
}

extern "C" void kernel_launch(void* const* d_in, const int* in_sizes, int n_in,
                              void* d_out, int out_size, void* d_ws, size_t ws_size,
                              hipStream_t stream) {
    const float* input1 = (const float*)d_in[0];
    const float* kl     = (const float*)d_in[1];
    const float* weight = (const float*)d_in[2];
    const int*   x_til  = (const int*)d_in[3];
    float* out = (float*)d_out;
    float* ws  = (float*)d_ws;

    vq_mega<<<NBLK, 256, 0, stream>>>(input1, x_til, weight, out, ws);
    vq_fin<<<1, 256, 0, stream>>>(x_til, ws, kl, out);
}

// Round 14
// 122.531 us; speedup vs baseline: 1.2992x; 1.2992x over previous
//
#include <hip/hip_runtime.h>

// Problem constants
constexpr int B_ = 32, C_ = 64, H_ = 64, W_ = 64, K_ = 1024;
constexpr int NTOT = B_ * C_ * H_ * W_;          // 8388608 elements of input1/quantized
constexpr int NSP  = B_ * H_ * W_;               // 131072 spatial positions
// d_out float offsets: [0]=loss, [1..32]=input2_KL, [33..33+NTOT)=quantized(BCHW),
// [OFF_ENC .. OFF_ENC+NSP*K)=encodings
constexpr int OFF_Q   = 33;
constexpr int OFF_ENC = OFF_Q + NTOT;            // 8388641 (byte 33554564 == 4 mod 64)
constexpr long long ENC_ELEMS = (long long)NSP * K_;   // 134217728 (2^27)
// (OFF_ENC + 15)*4 == 0 mod 64: fill starts 64B-LINE-aligned.
// Head (row 0, cols 0..14) and tail (last row, col 1023) patched in vq_fin.
constexpr int ENC_HEAD = 15;
constexpr int ENC_NQ = (int)((ENC_ELEMS - ENC_HEAD - 1) / 4);   // 33554428 quads
constexpr int ENC_BLOCKS = (ENC_NQ + 255) / 256;                // 131072 blocks

constexpr int MAIN_BLOCKS  = NSP / 64;                          // 2048 blocks
constexpr int TOTAL_BLOCKS = ENC_BLOCKS + MAIN_BLOCKS;          // 133120

typedef float v4f __attribute__((ext_vector_type(4)));

// Fused kernel, ENC FIRST / MAIN LAST (vs R10's main-first):
//  Blocks [0, ENC_BLOCKS): computed one-hot fill (exact R10 body) — runs from
//    t=0 at full store BW with nothing in front of it.
//  Blocks [ENC_BLOCKS, TOTAL_BLOCKS): quantized+loss (exact R10 body) — these
//    2048 blocks dispatch only as enc blocks drain, so their latency-bound,
//    low-BW work overlaps the tail of the store stream instead of serializing
//    ~20-25 us in front of it (R10) or polluting it throughout (R12).
__global__ __launch_bounds__(256) void vq_fused(const float* __restrict__ input1,
                                                const int*   __restrict__ x_tilde,
                                                const float* __restrict__ weight,
                                                float* __restrict__ out,  // d_out base
                                                float* __restrict__ ws) { // d_ws partials
    const int bid = blockIdx.x;
    if (bid < ENC_BLOCKS) {
        // ---- encodings fill path (rocclr fill shape: one 16B store/thread) ----
        const int b  = bid;
        const int qi = b * 256 + threadIdx.x;
        if (qi >= ENC_NQ) return;             // 4 idle threads in the last block
        const int t0 = x_tilde[b];
        const int t1 = x_tilde[(b + 1 < NSP) ? b + 1 : NSP - 1];
        const int col0 = ENC_HEAD + (threadIdx.x << 2);        // 15..1035 rel. row b
        v4f v;
        #pragma unroll
        for (int j = 0; j < 4; ++j) {
            const int col = col0 + j;
            ((float*)&v)[j] = (col < 1024) ? ((t0 == col) ? 1.f : 0.f)
                                           : ((t1 == col - 1024) ? 1.f : 0.f);
        }
        *reinterpret_cast<v4f*>(out + OFF_ENC + ENC_HEAD + (qi << 2)) = v;
        return;
    }

    // ---- quantized + loss path (transposed gather, 4-way channel split) ----
    const int mq  = bid - ENC_BLOCKS;                // 0..MAIN_BLOCKS-1
    const int tid = threadIdx.x;
    const int n   = mq * 64 + (tid & 63);            // [0, NSP)
    const int cq  = tid >> 6;                        // 0..3 -> channels 16cq..16cq+15
    const int b   = n >> 12;                         // H*W = 4096
    const int hw  = n & 4095;
    const int t   = x_tilde[n];
    const float* __restrict__ wrow = weight + (t << 6) + (cq << 4);
    const float* __restrict__ xin  = input1 + (b << 18) + (cq << 16) + hw;
    float* __restrict__ qout = out + OFF_Q + (b << 18) + (cq << 16) + hw;

    const float4 w0 = *reinterpret_cast<const float4*>(wrow);
    const float4 w1 = *reinterpret_cast<const float4*>(wrow + 4);
    const float4 w2 = *reinterpret_cast<const float4*>(wrow + 8);
    const float4 w3 = *reinterpret_cast<const float4*>(wrow + 12);
    const float wv[16] = {w0.x, w0.y, w0.z, w0.w, w1.x, w1.y, w1.z, w1.w,
                          w2.x, w2.y, w2.z, w2.w, w3.x, w3.y, w3.z, w3.w};
    float local = 0.f;
    #pragma unroll
    for (int j = 0; j < 16; ++j) {
        const float x = xin[j << 12];
        const float d = wv[j] - x;
        qout[j << 12] = x + d;       // straight-through: x + (q - x)
        local += d * d;
    }

    // wave64 reduce + one plain store per block (overwrites; no zeroing needed)
    for (int o = 32; o > 0; o >>= 1) local += __shfl_down(local, o);
    __shared__ float sm[4];
    const int lane = tid & 63, wid = tid >> 6;
    if (lane == 0) sm[wid] = local;
    __syncthreads();
    if (tid == 0) {
        ws[mq] = sm[0] + sm[1] + sm[2] + sm[3];
    }
}

// Finalize: reduce the 2048 partial sums -> loss, input2_KL passthrough, and
// the 16 edge elements the line-aligned fill skipped.
__global__ __launch_bounds__(256) void vq_fin(const int* __restrict__ x_tilde,
                                              const float* __restrict__ ws,
                                              const float* __restrict__ kl,
                                              float* __restrict__ out) {
    const int tid = threadIdx.x;
    float local = 0.f;
    #pragma unroll
    for (int k = 0; k < 8; ++k) local += ws[tid + (k << 8)];
    for (int o = 32; o > 0; o >>= 1) local += __shfl_down(local, o);
    __shared__ float sm[4];
    if ((tid & 63) == 0) sm[tid >> 6] = local;
    __syncthreads();
    if (tid == 0) out[0] = 1.25f * (sm[0] + sm[1] + sm[2] + sm[3]) / (float)NTOT;
    if (tid >= 64 && tid < 96) out[1 + tid - 64] = kl[tid - 64];
    if (tid == 96) {
        const int t0 = x_tilde[0];
        #pragma unroll
        for (int j = 0; j < ENC_HEAD; ++j)
            out[OFF_ENC + j] = (t0 == j) ? 1.f : 0.f;      // row 0, cols 0..14
        const int tl = x_tilde[NSP - 1];
        out[OFF_ENC + (int)ENC_ELEMS - 1] = (tl == 1023) ? 1.f : 0.f;
    }
}

extern "C" void kernel_launch(void* const* d_in, const int* in_sizes, int n_in,
                              void* d_out, int out_size, void* d_ws, size_t ws_size,
                              hipStream_t stream) {
    const float* input1 = (const float*)d_in[0];
    const float* kl     = (const float*)d_in[1];
    const float* weight = (const float*)d_in[2];
    const int*   x_til  = (const int*)d_in[3];
    float* out = (float*)d_out;
    float* ws  = (float*)d_ws;

    vq_fused<<<TOTAL_BLOCKS, 256, 0, stream>>>(input1, x_til, weight, out, ws);
    vq_fin<<<1, 256, 0, stream>>>(x_til, ws, kl, out);
}